// Round 5
// baseline (116.376 us; speedup 1.0000x reference)
//
#include <hip/hip_runtime.h>
#include <hip/hip_bf16.h>

// Flash-attention fwd, fp32 in/out, bf16 MFMA compute.
// B=64 (batch*heads), L=1024, D=64. scale = 1/sqrt(512). mask==true -> -1e9.
// R5: mask (int32, 81% of HBM traffic) staged via LDS with int4 vector loads,
//     packed to u8; apply phase reads LDS instead of 16 scalar global loads.

typedef __attribute__((ext_vector_type(4))) float f32x4;
typedef __attribute__((ext_vector_type(8))) short bf16x8;
typedef __attribute__((ext_vector_type(4))) short short4v;

constexpr int B_ = 64;
constexpr int L_ = 1024;
constexpr int D_ = 64;
constexpr int QBLK = 64;     // q rows per block (4 waves x 16)
constexpr int KV = 64;       // keys per tile
constexpr int NKV = L_ / KV; // 16 tiles
constexpr int PAD = 8;       // bf16 elements of row padding (16B)
constexpr int STR = KV + PAD; // 72 shorts per LDS row
constexpr int STRB = 72;      // mask row stride in bytes (64 + 8 pad, 4B-aligned)
constexpr float INV_TEMP = 0.04419417382415922f; // 1/sqrt(512)
constexpr float NEG = -1e9f;

__device__ inline short f2bf(float f) {
  __hip_bfloat16 h = __float2bfloat16(f);
  short s; __builtin_memcpy(&s, &h, 2);
  return s;
}

__global__ __launch_bounds__(256) void attn_fwd(
    const float* __restrict__ Q, const float* __restrict__ K,
    const float* __restrict__ V, const int* __restrict__ M,
    float* __restrict__ O)
{
  __shared__ short k_lds[KV][STR];          // K tile, [key][d]
  __shared__ short vt_lds[D_][STR];         // V tile transposed, [d][key]
  __shared__ short p_lds[4][16][STR];       // per-wave P relayout buffer
  __shared__ unsigned char m_lds[QBLK][STRB]; // mask tile, 1B/elem [qrow][key]

  const int qt   = blockIdx.x;
  const int b    = blockIdx.y;
  const int tid  = threadIdx.x;
  const int w    = tid >> 6;
  const int lane = tid & 63;
  const int g    = lane >> 4; // 16-lane group 0..3
  const int c    = lane & 15;

  const int q0 = qt * QBLK;

  // ---- Q fragments (A operand of QK^T): row = lane&15, k(d) = ks*32 + g*8 + j
  bf16x8 qf[2];
  {
    const int qrow = q0 + w * 16 + c;
    const float* qp = Q + ((size_t)b * L_ + qrow) * D_ + g * 8;
#pragma unroll
    for (int ks = 0; ks < 2; ++ks) {
      f32x4 x0 = *(const f32x4*)(qp + ks * 32);
      f32x4 x1 = *(const f32x4*)(qp + ks * 32 + 4);
      bf16x8 t;
      t[0] = f2bf(x0[0]); t[1] = f2bf(x0[1]); t[2] = f2bf(x0[2]); t[3] = f2bf(x0[3]);
      t[4] = f2bf(x1[0]); t[5] = f2bf(x1[1]); t[6] = f2bf(x1[2]); t[7] = f2bf(x1[3]);
      qf[ks] = t;
    }
  }

  const float* Kb = K + (size_t)b * L_ * D_;
  const float* Vb = V + (size_t)b * L_ * D_;
  const int*   Mb = M + (size_t)b * L_ * L_ + (size_t)q0 * L_; // [qrow][key], row stride L_

  f32x4 acc[4];
#pragma unroll
  for (int i = 0; i < 4; ++i) acc[i] = (f32x4){0.f, 0.f, 0.f, 0.f};
  float m_run[4] = {-INFINITY, -INFINITY, -INFINITY, -INFINITY};
  float l_run[4] = {0.f, 0.f, 0.f, 0.f};

  for (int t = 0; t < NKV; ++t) {
    const int k0 = t * KV;

    // ---- stage K tile -> k_lds[key][d], V tile -> vt_lds[d][key] (bf16),
    //      mask tile -> m_lds[qrow][key] (u8), all with 16B vector global loads
    {
      const float* ksrc = Kb + (size_t)k0 * D_;
      const float* vsrc = Vb + (size_t)k0 * D_;
      const int*   msrc = Mb + k0;
#pragma unroll
      for (int i = 0; i < 4; ++i) {
        const int idx = tid + i * 256;   // float4 index in 64x64 tile
        const int key = idx >> 4;        // 16 float4 per row
        const int d4  = (idx & 15) * 4;
        f32x4 kx = *(const f32x4*)(ksrc + (size_t)idx * 4);
        short4v ks4 = { f2bf(kx[0]), f2bf(kx[1]), f2bf(kx[2]), f2bf(kx[3]) };
        *(short4v*)&k_lds[key][d4] = ks4;
        f32x4 vx = *(const f32x4*)(vsrc + (size_t)idx * 4);
        vt_lds[d4 + 0][key] = f2bf(vx[0]);
        vt_lds[d4 + 1][key] = f2bf(vx[1]);
        vt_lds[d4 + 2][key] = f2bf(vx[2]);
        vt_lds[d4 + 3][key] = f2bf(vx[3]);
        // mask: same idx decomposition, int4 = 4 consecutive keys of one q-row
        const int4 mm = *(const int4*)(msrc + (size_t)key * L_ + d4);
        unsigned int packed = (unsigned int)(mm.x != 0)
                            | ((unsigned int)(mm.y != 0) << 8)
                            | ((unsigned int)(mm.z != 0) << 16)
                            | ((unsigned int)(mm.w != 0) << 24);
        *(unsigned int*)&m_lds[key][d4] = packed;  // here key==qrow, d4==key-col
      }
    }
    __syncthreads();

    // ---- S = Q K^T : 4 key-fragments of 16, 2 K-slices of 32 over D
    f32x4 sc[4];
#pragma unroll
    for (int f = 0; f < 4; ++f) {
      f32x4 a = (f32x4){0.f, 0.f, 0.f, 0.f};
#pragma unroll
      for (int ks = 0; ks < 2; ++ks) {
        bf16x8 kf = *(const bf16x8*)&k_lds[f * 16 + c][ks * 32 + g * 8];
        a = __builtin_amdgcn_mfma_f32_16x16x32_bf16(qf[ks], kf, a, 0, 0, 0);
      }
      sc[f] = a;
    }

    // ---- scale + mask from LDS (mask true -> -1e9). C layout: row=g*4+r, col=f*16+c
#pragma unroll
    for (int f = 0; f < 4; ++f) {
#pragma unroll
      for (int r = 0; r < 4; ++r) {
        unsigned char mm = m_lds[w * 16 + g * 4 + r][f * 16 + c];
        sc[f][r] = mm ? NEG : sc[f][r] * INV_TEMP;
      }
    }

    // ---- online softmax (rows g*4+r live in the 16 lanes of group g)
    float m_new[4], alpha[4];
#pragma unroll
    for (int r = 0; r < 4; ++r) {
      float x = fmaxf(fmaxf(sc[0][r], sc[1][r]), fmaxf(sc[2][r], sc[3][r]));
#pragma unroll
      for (int sh = 1; sh < 16; sh <<= 1) x = fmaxf(x, __shfl_xor(x, sh, 64));
      m_new[r] = fmaxf(m_run[r], x);
      alpha[r] = __expf(m_run[r] - m_new[r]);
    }
#pragma unroll
    for (int f = 0; f < 4; ++f)
#pragma unroll
      for (int r = 0; r < 4; ++r)
        sc[f][r] = __expf(sc[f][r] - m_new[r]);
#pragma unroll
    for (int r = 0; r < 4; ++r) {
      float s = (sc[0][r] + sc[1][r]) + (sc[2][r] + sc[3][r]);
#pragma unroll
      for (int sh = 1; sh < 16; sh <<= 1) s += __shfl_xor(s, sh, 64);
      l_run[r] = l_run[r] * alpha[r] + s;
      m_run[r] = m_new[r];
    }
#pragma unroll
    for (int fd = 0; fd < 4; ++fd)
#pragma unroll
      for (int r = 0; r < 4; ++r) acc[fd][r] *= alpha[r];

    // ---- P -> LDS (bf16), C-layout -> A-layout relayout (within-wave, DS in-order)
#pragma unroll
    for (int f = 0; f < 4; ++f)
#pragma unroll
      for (int r = 0; r < 4; ++r)
        p_lds[w][g * 4 + r][f * 16 + c] = f2bf(sc[f][r]);

    // ---- O += P V : A = p_lds row c, B = vt_lds (V^T)
#pragma unroll
    for (int ks = 0; ks < 2; ++ks) {
      bf16x8 pa = *(const bf16x8*)&p_lds[w][c][ks * 32 + g * 8];
#pragma unroll
      for (int fd = 0; fd < 4; ++fd) {
        bf16x8 vb = *(const bf16x8*)&vt_lds[fd * 16 + c][ks * 32 + g * 8];
        acc[fd] = __builtin_amdgcn_mfma_f32_16x16x32_bf16(pa, vb, acc[fd], 0, 0, 0);
      }
    }
    __syncthreads();
  }

  // ---- epilogue: divide by l, store fp32
  float inv_l[4];
#pragma unroll
  for (int r = 0; r < 4; ++r) inv_l[r] = 1.0f / l_run[r];
  float* orow = O + ((size_t)b * L_ + q0 + w * 16 + g * 4) * D_;
#pragma unroll
  for (int fd = 0; fd < 4; ++fd)
#pragma unroll
    for (int r = 0; r < 4; ++r)
      orow[(size_t)r * D_ + fd * 16 + c] = acc[fd][r] * inv_l[r];
}

extern "C" void kernel_launch(void* const* d_in, const int* in_sizes, int n_in,
                              void* d_out, int out_size, void* d_ws, size_t ws_size,
                              hipStream_t stream) {
  const float* q = (const float*)d_in[0];
  const float* k = (const float*)d_in[1];
  const float* v = (const float*)d_in[2];
  const int* m = (const int*)d_in[3]; // jax bool shipped as int32
  float* o = (float*)d_out;
  dim3 grid(L_ / QBLK, B_);
  attn_fwd<<<grid, 256, 0, stream>>>(q, k, v, m, o);
}

// Round 6
// 104.843 us; speedup vs baseline: 1.1100x; 1.1100x over previous
//
#include <hip/hip_runtime.h>
#include <hip/hip_bf16.h>

// Flash-attention fwd, fp32 in/out, bf16 MFMA compute.
// B=64 (batch*heads), L=1024, D=64. scale = 1/sqrt(512). mask==true -> -1e9.
// R6: (1) register-prefetch staging overlapped with compute (single LDS buffer,
//     loads for tile t+1 issued before compute of tile t, written after barrier);
//     (2) V-transpose write-order rotation to break the 16-way bank conflict.

typedef __attribute__((ext_vector_type(4))) float f32x4;
typedef __attribute__((ext_vector_type(8))) short bf16x8;
typedef __attribute__((ext_vector_type(4))) short short4v;

constexpr int B_ = 64;
constexpr int L_ = 1024;
constexpr int D_ = 64;
constexpr int QBLK = 64;     // q rows per block (4 waves x 16)
constexpr int KV = 64;       // keys per tile
constexpr int NKV = L_ / KV; // 16 tiles
constexpr int PAD = 8;       // bf16 elements of row padding (16B)
constexpr int STR = KV + PAD; // 72 shorts per LDS row
constexpr int STRB = 72;      // mask row stride in bytes
constexpr float INV_TEMP = 0.04419417382415922f; // 1/sqrt(512)
constexpr float NEG = -1e9f;

__device__ inline short f2bf(float f) {
  __hip_bfloat16 h = __float2bfloat16(f);
  short s; __builtin_memcpy(&s, &h, 2);
  return s;
}

__global__ __launch_bounds__(256) void attn_fwd(
    const float* __restrict__ Q, const float* __restrict__ K,
    const float* __restrict__ V, const int* __restrict__ M,
    float* __restrict__ O)
{
  __shared__ short k_lds[KV][STR];            // K tile, [key][d]
  __shared__ short vt_lds[D_][STR];           // V tile transposed, [d][key]
  __shared__ short p_lds[4][16][STR];         // per-wave P relayout buffer
  __shared__ unsigned char m_lds[QBLK][STRB]; // mask tile, 1B/elem [qrow][key]

  const int qt   = blockIdx.x;
  const int b    = blockIdx.y;
  const int tid  = threadIdx.x;
  const int w    = tid >> 6;
  const int lane = tid & 63;
  const int g    = lane >> 4; // 16-lane group 0..3
  const int c    = lane & 15;

  const int q0 = qt * QBLK;

  // ---- Q fragments (A operand of QK^T): row = lane&15, k(d) = ks*32 + g*8 + j
  bf16x8 qf[2];
  {
    const int qrow = q0 + w * 16 + c;
    const float* qp = Q + ((size_t)b * L_ + qrow) * D_ + g * 8;
#pragma unroll
    for (int ks = 0; ks < 2; ++ks) {
      f32x4 x0 = *(const f32x4*)(qp + ks * 32);
      f32x4 x1 = *(const f32x4*)(qp + ks * 32 + 4);
      bf16x8 t;
      t[0] = f2bf(x0[0]); t[1] = f2bf(x0[1]); t[2] = f2bf(x0[2]); t[3] = f2bf(x0[3]);
      t[4] = f2bf(x1[0]); t[5] = f2bf(x1[1]); t[6] = f2bf(x1[2]); t[7] = f2bf(x1[3]);
      qf[ks] = t;
    }
  }

  const float* Kb = K + (size_t)b * L_ * D_;
  const float* Vb = V + (size_t)b * L_ * D_;
  const int*   Mb = M + (size_t)b * L_ * L_ + (size_t)q0 * L_; // [qrow][key]

  // ---- prefetch registers (held across compute; expect VGPR ~110)
  f32x4 kreg[4], vreg[4];
  int4  mreg[4];

  auto stage_load = [&](int t) {
    const float* ksrc = Kb + (size_t)(t * KV) * D_;
    const float* vsrc = Vb + (size_t)(t * KV) * D_;
    const int*   msrc = Mb + t * KV;
#pragma unroll
    for (int i = 0; i < 4; ++i) {
      const int idx = tid + i * 256;   // float4 index in 64x64 tile
      const int key = idx >> 4;
      const int d4  = (idx & 15) * 4;
      kreg[i] = *(const f32x4*)(ksrc + (size_t)idx * 4);
      vreg[i] = *(const f32x4*)(vsrc + (size_t)idx * 4);
      mreg[i] = *(const int4*)(msrc + (size_t)key * L_ + d4);
    }
  };

  auto stage_write = [&]() {
    const int rot = (tid & 15) >> 1; // decorrelate bank = f(row) across lanes
#pragma unroll
    for (int i = 0; i < 4; ++i) {
      const int idx = tid + i * 256;
      const int key = idx >> 4;
      const int d4  = (idx & 15) * 4;
      f32x4 kx = kreg[i];
      short4v ks4 = { f2bf(kx[0]), f2bf(kx[1]), f2bf(kx[2]), f2bf(kx[3]) };
      *(short4v*)&k_lds[key][d4] = ks4;
      f32x4 vx = vreg[i];
#pragma unroll
      for (int j = 0; j < 4; ++j) {
        const int jj = (j + rot) & 3;          // write order rotated per lane;
        vt_lds[d4 + jj][key] = f2bf(vx[jj]);   // each element -> its own (d,key)
      }
      int4 mm = mreg[i];
      unsigned int packed = (unsigned int)(mm.x != 0)
                          | ((unsigned int)(mm.y != 0) << 8)
                          | ((unsigned int)(mm.z != 0) << 16)
                          | ((unsigned int)(mm.w != 0) << 24);
      *(unsigned int*)&m_lds[key][d4] = packed;
    }
  };

  f32x4 acc[4];
#pragma unroll
  for (int i = 0; i < 4; ++i) acc[i] = (f32x4){0.f, 0.f, 0.f, 0.f};
  float m_run[4] = {-INFINITY, -INFINITY, -INFINITY, -INFINITY};
  float l_run[4] = {0.f, 0.f, 0.f, 0.f};

  // prologue: tile 0 staged serially
  stage_load(0);
  stage_write();
  __syncthreads();

  for (int t = 0; t < NKV; ++t) {
    const bool has_next = (t + 1 < NKV);
    if (has_next) stage_load(t + 1);   // issue early; latency hides under compute

    // ---- S = Q K^T
    f32x4 sc[4];
#pragma unroll
    for (int f = 0; f < 4; ++f) {
      f32x4 a = (f32x4){0.f, 0.f, 0.f, 0.f};
#pragma unroll
      for (int ks = 0; ks < 2; ++ks) {
        bf16x8 kf = *(const bf16x8*)&k_lds[f * 16 + c][ks * 32 + g * 8];
        a = __builtin_amdgcn_mfma_f32_16x16x32_bf16(qf[ks], kf, a, 0, 0, 0);
      }
      sc[f] = a;
    }

    // ---- scale + mask from LDS. C layout: row = g*4+r, col = f*16+c
#pragma unroll
    for (int f = 0; f < 4; ++f) {
#pragma unroll
      for (int r = 0; r < 4; ++r) {
        unsigned char mm = m_lds[w * 16 + g * 4 + r][f * 16 + c];
        sc[f][r] = mm ? NEG : sc[f][r] * INV_TEMP;
      }
    }

    // ---- online softmax (rows g*4+r live in the 16 lanes of group g)
    float m_new[4], alpha[4];
#pragma unroll
    for (int r = 0; r < 4; ++r) {
      float x = fmaxf(fmaxf(sc[0][r], sc[1][r]), fmaxf(sc[2][r], sc[3][r]));
#pragma unroll
      for (int sh = 1; sh < 16; sh <<= 1) x = fmaxf(x, __shfl_xor(x, sh, 64));
      m_new[r] = fmaxf(m_run[r], x);
      alpha[r] = __expf(m_run[r] - m_new[r]);
    }
#pragma unroll
    for (int f = 0; f < 4; ++f)
#pragma unroll
      for (int r = 0; r < 4; ++r)
        sc[f][r] = __expf(sc[f][r] - m_new[r]);
#pragma unroll
    for (int r = 0; r < 4; ++r) {
      float s = (sc[0][r] + sc[1][r]) + (sc[2][r] + sc[3][r]);
#pragma unroll
      for (int sh = 1; sh < 16; sh <<= 1) s += __shfl_xor(s, sh, 64);
      l_run[r] = l_run[r] * alpha[r] + s;
      m_run[r] = m_new[r];
    }
#pragma unroll
    for (int fd = 0; fd < 4; ++fd)
#pragma unroll
      for (int r = 0; r < 4; ++r) acc[fd][r] *= alpha[r];

    // ---- P -> LDS (bf16), C-layout -> A-layout relayout (per-wave buffer)
#pragma unroll
    for (int f = 0; f < 4; ++f)
#pragma unroll
      for (int r = 0; r < 4; ++r)
        p_lds[w][g * 4 + r][f * 16 + c] = f2bf(sc[f][r]);

    // ---- O += P V
#pragma unroll
    for (int ks = 0; ks < 2; ++ks) {
      bf16x8 pa = *(const bf16x8*)&p_lds[w][c][ks * 32 + g * 8];
#pragma unroll
      for (int fd = 0; fd < 4; ++fd) {
        bf16x8 vb = *(const bf16x8*)&vt_lds[fd * 16 + c][ks * 32 + g * 8];
        acc[fd] = __builtin_amdgcn_mfma_f32_16x16x32_bf16(pa, vb, acc[fd], 0, 0, 0);
      }
    }

    __syncthreads();                  // all waves done reading tile t
    if (has_next) stage_write();      // overwrite LDS with tile t+1
    __syncthreads();                  // tile t+1 visible
  }

  // ---- epilogue: divide by l, store fp32
  float inv_l[4];
#pragma unroll
  for (int r = 0; r < 4; ++r) inv_l[r] = 1.0f / l_run[r];
  float* orow = O + ((size_t)b * L_ + q0 + w * 16 + g * 4) * D_;
#pragma unroll
  for (int fd = 0; fd < 4; ++fd)
#pragma unroll
    for (int r = 0; r < 4; ++r)
      orow[(size_t)r * D_ + fd * 16 + c] = acc[fd][r] * inv_l[r];
}

extern "C" void kernel_launch(void* const* d_in, const int* in_sizes, int n_in,
                              void* d_out, int out_size, void* d_ws, size_t ws_size,
                              hipStream_t stream) {
  const float* q = (const float*)d_in[0];
  const float* k = (const float*)d_in[1];
  const float* v = (const float*)d_in[2];
  const int* m = (const int*)d_in[3]; // jax bool shipped as int32
  float* o = (float*)d_out;
  dim3 grid(L_ / QBLK, B_);
  attn_fwd<<<grid, 256, 0, stream>>>(q, k, v, m, o);
}